// Round 1
// baseline (4836.569 us; speedup 1.0000x reference)
//
#include <hip/hip_runtime.h>
#include <cstdint>
#include <cstddef>

#define HID    128
#define K1     385      // 3*HID + 1
#define EPB    8        // edges per block in edge kernel
#define NLAYER 4
#define NNODES 2048
#define NEDGES 129024
#define DEG    63

__device__ __forceinline__ float silu_f(float v) {
    return v / (1.0f + __expf(-v));
}

// h_ws = h_in @ emb_w + emb_b ; also copy x into working buffer
__global__ __launch_bounds__(128) void embed_kernel(
    const float* __restrict__ h_in, const float* __restrict__ emb_w,
    const float* __restrict__ emb_b, float* __restrict__ h_ws,
    const float* __restrict__ x_in, float* __restrict__ x_a)
{
    const int n = blockIdx.x;
    const int o = threadIdx.x;
    __shared__ float hin[32];
    if (o < 32) hin[o] = h_in[n * 32 + o];
    __syncthreads();
    float acc = emb_b[o];
#pragma unroll
    for (int k = 0; k < 32; ++k) acc += hin[k] * emb_w[k * HID + o];
    h_ws[n * HID + o] = acc;
    if (o < 3) x_a[n * 3 + o] = x_in[n * 3 + o];
}

// Fused per-edge: e_in -> silu(W1) -> silu(W2)=m -> coord scalar c.
// Writes m (next layer's edge_attr) and c.
__global__ __launch_bounds__(1024) void edge_kernel(
    const float* __restrict__ h, const float* __restrict__ x,
    const int* __restrict__ erow, const int* __restrict__ ecol,
    const float* __restrict__ ea_in, float* __restrict__ ea_out,
    const float* __restrict__ W1, const float* __restrict__ b1,
    const float* __restrict__ W2, const float* __restrict__ b2,
    const float* __restrict__ cW1, const float* __restrict__ cb1,
    const float* __restrict__ cW2, float* __restrict__ c_out)
{
    __shared__ float ein[EPB][K1];
    __shared__ float hid[EPB][HID];
    __shared__ float mld[EPB][HID];
    __shared__ float red[EPB][2];
    const int t  = threadIdx.x;
    const int o  = t & (HID - 1);
    const int el = t >> 7;
    const int e  = blockIdx.x * EPB + el;
    const int row = erow[e], col = ecol[e];
    const size_t ebase = (size_t)e * HID;

    // stage e_in = [h_row(128) | h_col(128) | radial(1) | edge_attr(128)]
    ein[el][o]         = h[row * HID + o];
    ein[el][HID + o]   = h[col * HID + o];
    ein[el][257 + o]   = ea_in[ebase + o];
    const float dx = x[row * 3 + 0] - x[col * 3 + 0];
    const float dy = x[row * 3 + 1] - x[col * 3 + 1];
    const float dz = x[row * 3 + 2] - x[col * 3 + 2];
    if (o == 0) ein[el][256] = dx * dx + dy * dy + dz * dz;
    __syncthreads();

    // edge MLP layer 1: K=385
    float acc = b1[o];
    for (int k = 0; k < K1; ++k) acc += ein[el][k] * W1[k * HID + o];
    hid[el][o] = silu_f(acc);
    __syncthreads();

    // edge MLP layer 2: K=128
    acc = b2[o];
    for (int k = 0; k < HID; ++k) acc += hid[el][k] * W2[k * HID + o];
    const float mo = silu_f(acc);
    ea_out[ebase + o] = mo;
    mld[el][o] = mo;
    __syncthreads();

    // coord MLP: silu(m @ cW1 + cb1) @ cW2  (scalar per edge)
    acc = cb1[o];
    for (int k = 0; k < HID; ++k) acc += mld[el][k] * cW1[k * HID + o];
    float cv = silu_f(acc) * cW2[o];
#pragma unroll
    for (int off = 32; off > 0; off >>= 1) cv += __shfl_xor(cv, off);
    if ((t & 63) == 0) red[el][(t >> 6) & 1] = cv;
    __syncthreads();
    if (o == 0) c_out[e] = red[el][0] + red[el][1];
}

// Per-node: agg = sum_m over this node's 63 contiguous edges; node MLP
// (residual); coordinate update x_out = x_in + sum(c*diff)/63.
__global__ __launch_bounds__(128) void node_kernel(
    float* __restrict__ h, const float* __restrict__ x_in, float* __restrict__ x_out,
    const float* __restrict__ m, const float* __restrict__ c_ws,
    const int* __restrict__ ecol,
    const float* __restrict__ nW1, const float* __restrict__ nb1,
    const float* __restrict__ nW2, const float* __restrict__ nb2,
    float* __restrict__ out, const int write_out)
{
    const int n = blockIdx.x;
    const int o = threadIdx.x;
    __shared__ float nin[2 * HID];
    __shared__ float hidl[HID];
    const float hval = h[n * HID + o];
    const size_t mbase = (size_t)n * DEG * HID;
    float agg = 0.0f;
    for (int k = 0; k < DEG; ++k) agg += m[mbase + (size_t)k * HID + o];
    nin[o]       = hval;
    nin[HID + o] = agg;
    __syncthreads();
    float acc = nb1[o];
    for (int k = 0; k < 2 * HID; ++k) acc += nin[k] * nW1[k * HID + o];
    hidl[o] = silu_f(acc);
    __syncthreads();
    acc = nb2[o];
    for (int k = 0; k < HID; ++k) acc += hidl[k] * nW2[k * HID + o];
    const float hnew = hval + acc;
    h[n * HID + o] = hnew;
    if (write_out) out[n * HID + o] = hnew;

    if (o < 3) {
        const float xi = x_in[n * 3 + o];
        float s = 0.0f;
        const int ebase = n * DEG;
        for (int k = 0; k < DEG; ++k) {
            const int col = ecol[ebase + k];
            s += c_ws[ebase + k] * (xi - x_in[col * 3 + o]);
        }
        x_out[n * 3 + o] = xi + s * (1.0f / DEG);
    }
}

extern "C" void kernel_launch(void* const* d_in, const int* in_sizes, int n_in,
                              void* d_out, int out_size, void* d_ws, size_t ws_size,
                              hipStream_t stream)
{
    const float* h_in  = (const float*)d_in[0];
    const float* x_in  = (const float*)d_in[1];
    const int*   erow  = (const int*)d_in[2];
    const int*   ecol  = (const int*)d_in[3];
    const float* ea0   = (const float*)d_in[4];
    const float* emb_w = (const float*)d_in[5];
    const float* emb_b = (const float*)d_in[6];
    const float* eW1   = (const float*)d_in[7];
    const float* eB1   = (const float*)d_in[8];
    const float* eW2   = (const float*)d_in[9];
    const float* eB2   = (const float*)d_in[10];
    const float* nW1   = (const float*)d_in[11];
    const float* nB1   = (const float*)d_in[12];
    const float* nW2   = (const float*)d_in[13];
    const float* nB2   = (const float*)d_in[14];
    const float* cW1   = (const float*)d_in[15];
    const float* cB1   = (const float*)d_in[16];
    const float* cW2   = (const float*)d_in[17];
    float* out = (float*)d_out;

    float* ws    = (float*)d_ws;
    float* h_ws  = ws;                          // NNODES*HID
    float* x_a   = h_ws + (size_t)NNODES * HID; // NNODES*3
    float* x_b   = x_a + NNODES * 3;            // NNODES*3
    float* c_ws  = x_b + NNODES * 3;            // NEDGES
    float* ea_ws = c_ws + NEDGES;               // NEDGES*HID
    const size_t need = ((size_t)NNODES * HID + 2u * NNODES * 3 + NEDGES
                         + (size_t)NEDGES * HID) * sizeof(float);
    if (ws_size < need) {
        // fallback: write m in place over the edge_attr input (restored by
        // harness before every launch; per-edge read-then-write is safe)
        ea_ws = (float*)d_in[4];
    }

    embed_kernel<<<NNODES, HID, 0, stream>>>(h_in, emb_w, emb_b, h_ws, x_in, x_a);

    float* xc = x_a;
    float* xn = x_b;
    const float* ein_ptr = ea0;
    for (int i = 0; i < NLAYER; ++i) {
        edge_kernel<<<NEDGES / EPB, EPB * HID, 0, stream>>>(
            h_ws, xc, erow, ecol, ein_ptr, ea_ws,
            eW1 + (size_t)i * K1 * HID, eB1 + i * HID,
            eW2 + (size_t)i * HID * HID, eB2 + i * HID,
            cW1 + (size_t)i * HID * HID, cB1 + i * HID,
            cW2 + (size_t)i * HID, c_ws);
        node_kernel<<<NNODES, HID, 0, stream>>>(
            h_ws, xc, xn, ea_ws, c_ws, ecol,
            nW1 + (size_t)i * 2 * HID * HID, nB1 + i * HID,
            nW2 + (size_t)i * HID * HID, nB2 + i * HID,
            out, (i == NLAYER - 1) ? 1 : 0);
        float* tmp = xc; xc = xn; xn = tmp;
        ein_ptr = ea_ws;
    }
}

// Round 3
// 493.194 us; speedup vs baseline: 9.8066x; 9.8066x over previous
//
#include <hip/hip_runtime.h>
#include <cstdint>
#include <cstddef>

#define HID    128
#define K1     385
#define NLAYER 4
#define NNODES 2048
#define NEDGES 129024
#define DEG    63
#define EPB    64               // edges (M rows) per block
#define EBLOCKS (NEDGES / EPB)  // 2016
#define EA_STRIDE 256           // shorts per edge row in the aliased bf16 buffer
                                // (512 B == one f32 row of the original edge_attr)

typedef __attribute__((ext_vector_type(8))) short short8;
typedef __attribute__((ext_vector_type(4))) float f32x4;

__device__ __forceinline__ unsigned short f2bf(float f) {
    unsigned int u = __builtin_bit_cast(unsigned int, f);
    unsigned int r = u + 0x7fffu + ((u >> 16) & 1u);
    return (unsigned short)(r >> 16);
}
__device__ __forceinline__ float bf2f(unsigned short h) {
    unsigned int u = ((unsigned int)h) << 16;
    return __builtin_bit_cast(float, u);
}
__device__ __forceinline__ float silu_f(float v) {
    return v / (1.0f + __expf(-v));
}

// ---------------- weight packing: row-major f32 (K x 128) -> fragment-linear bf16
// packed[((kk*8 + tn)*64 + lane)*8 + j] = W[rowmap(kk*32 + (lane>>4)*8 + j)][tn*16 + (lane&15)]
__global__ __launch_bounds__(64) void pack_w_kernel(
    const float* __restrict__ src, unsigned short* __restrict__ dst,
    const int KK, const int srcLayerStride, const int skip)
{
    int b = blockIdx.x;
    const int tn = b & 7; b >>= 3;
    const int kk = b % KK;
    const int layer = b / KK;
    const int lane = threadIdx.x, lq = lane >> 4, lr = lane & 15;
    const float* s = src + (size_t)layer * srcLayerStride;
    unsigned short* d = dst + (size_t)layer * (KK * 8 * 64 * 8)
                            + ((size_t)(kk * 8 + tn) * 64 + lane) * 8;
#pragma unroll
    for (int j = 0; j < 8; ++j) {
        const int kd = kk * 32 + lq * 8 + j;
        const int ka = (skip && kd >= 256) ? kd + 1 : kd;
        d[j] = f2bf(s[(size_t)ka * HID + tn * 16 + lr]);
    }
}

// ---------------- embedding: h = h_in @ emb_w + emb_b (f32 + bf16 shadow); copy x
__global__ __launch_bounds__(128) void embed_kernel(
    const float* __restrict__ h_in, const float* __restrict__ emb_w,
    const float* __restrict__ emb_b, float* __restrict__ h_ws,
    unsigned short* __restrict__ h_bf,
    const float* __restrict__ x_in, float* __restrict__ x_a)
{
    const int n = blockIdx.x;
    const int o = threadIdx.x;
    __shared__ float hin[32];
    if (o < 32) hin[o] = h_in[n * 32 + o];
    __syncthreads();
    float acc = emb_b[o];
#pragma unroll
    for (int k = 0; k < 32; ++k) acc += hin[k] * emb_w[k * HID + o];
    h_ws[n * HID + o] = acc;
    h_bf[n * HID + o] = f2bf(acc);
    if (o < 3) x_a[n * 3 + o] = x_in[n * 3 + o];
}

// ---------------- fused edge kernel (MFMA): e_in -> silu(W1) -> silu(W2)=m -> coord scalar
// LDS map (bytes):
//   [0, 49152)      einA  [64][384] bf16, row stride 768, XOR-swizzled
//   [0, 16384)      hid   [64][128] bf16 (after GEMM1, einA dead)
//   [16384, 32768)  m     [64][128] bf16
//   [32768, 33792)  red   [4][64] f32
//   [49152, 49408)  radial[64] f32
__global__ __launch_bounds__(256) void edge_mfma_kernel(
    const unsigned short* __restrict__ h_bf, const float* __restrict__ x,
    const int* __restrict__ erow, const int* __restrict__ ecol,
    const float* __restrict__ ea_f32,        // layer-0 edge_attr (f32), same buffer
    unsigned short* __restrict__ ea,         // bf16 edge rows @ stride EA_STRIDE (aliased)
    const int first_layer,
    const short8* __restrict__ w1p, const float* __restrict__ b1, const float* __restrict__ w256,
    const short8* __restrict__ w2p, const float* __restrict__ b2,
    const short8* __restrict__ cw1p, const float* __restrict__ cb1, const float* __restrict__ cw2,
    float* __restrict__ c_out)
{
    __shared__ __align__(16) char smem[49408];
    float* radial = (float*)(smem + 49152);
    float* red    = (float*)(smem + 32768);
    const int t = threadIdx.x;
    const int wave = t >> 6, lane = t & 63, lq = lane >> 4, lr = lane & 15;
    const int ebase = blockIdx.x * EPB;

    // ---- stage e_in = [h_row | h_col | edge_attr] as bf16 (radial separate) ----
    {
        const int el = t >> 2, sub = t & 3;
        const int e = ebase + el;
        const int row = erow[e], col = ecol[e];
        if (sub == 0) {
            const float dx = x[row * 3 + 0] - x[col * 3 + 0];
            const float dy = x[row * 3 + 1] - x[col * 3 + 1];
            const float dz = x[row * 3 + 2] - x[col * 3 + 2];
            radial[el] = dx * dx + dy * dy + dz * dz;
        }
        const uint4* hr = (const uint4*)(h_bf + (size_t)row * HID);
        const uint4* hc = (const uint4*)(h_bf + (size_t)col * HID);
        const uint4* ev = (const uint4*)(ea + (size_t)e * EA_STRIDE);
        const float4* ef = (const float4*)(ea_f32 + (size_t)e * HID);
        const int swz = (el & 7) << 4;
#pragma unroll
        for (int i = 0; i < 12; ++i) {
            const int c = sub * 12 + i;
            uint4 v;
            if (c < 16) v = hr[c];
            else if (c < 32) v = hc[c - 16];
            else if (!first_layer) v = ev[c - 32];
            else {
                const float4 f0 = ef[(c - 32) * 2];
                const float4 f1 = ef[(c - 32) * 2 + 1];
                v.x = (unsigned)f2bf(f0.x) | ((unsigned)f2bf(f0.y) << 16);
                v.y = (unsigned)f2bf(f0.z) | ((unsigned)f2bf(f0.w) << 16);
                v.z = (unsigned)f2bf(f1.x) | ((unsigned)f2bf(f1.y) << 16);
                v.w = (unsigned)f2bf(f1.z) | ((unsigned)f2bf(f1.w) << 16);
            }
            *(uint4*)(smem + el * 768 + ((c * 16) ^ swz)) = v;
        }
    }
    __syncthreads();

    // ---- GEMM1: einA(64x384) @ W1dense(384x128), wave owns cols [wave*32, wave*32+32) ----
    f32x4 acc[4][2] = {};
#pragma unroll
    for (int kk = 0; kk < 12; ++kk) {
        const short8 bf0 = w1p[(kk * 8 + wave * 2 + 0) * 64 + lane];
        const short8 bf1 = w1p[(kk * 8 + wave * 2 + 1) * 64 + lane];
#pragma unroll
        for (int mt = 0; mt < 4; ++mt) {
            const int r = mt * 16 + lr;
            const short8 af = *(const short8*)(smem + r * 768 + ((kk * 64 + lq * 16) ^ ((r & 7) << 4)));
            acc[mt][0] = __builtin_amdgcn_mfma_f32_16x16x32_bf16(af, bf0, acc[mt][0], 0, 0, 0);
            acc[mt][1] = __builtin_amdgcn_mfma_f32_16x16x32_bf16(af, bf1, acc[mt][1], 0, 0, 0);
        }
    }
    __syncthreads();   // all einA reads done; hid region may be overwritten

    // ---- epilogue 1: hid = silu(acc + b1 + radial * w256_row) ----
    {
        const int c0 = wave * 32 + lr, c1 = c0 + 16;
        const float bb0 = b1[c0], bb1 = b1[c1];
        const float ww0 = w256[c0], ww1 = w256[c1];
#pragma unroll
        for (int mt = 0; mt < 4; ++mt)
#pragma unroll
            for (int reg = 0; reg < 4; ++reg) {
                const int r = mt * 16 + lq * 4 + reg;
                const float rad = radial[r];
                const int swz = (r & 7) << 4;
                const float v0 = silu_f(acc[mt][0][reg] + bb0 + rad * ww0);
                const float v1 = silu_f(acc[mt][1][reg] + bb1 + rad * ww1);
                *(unsigned short*)(smem + r * 256 + ((c0 * 2) ^ swz)) = f2bf(v0);
                *(unsigned short*)(smem + r * 256 + ((c1 * 2) ^ swz)) = f2bf(v1);
            }
    }
    __syncthreads();

    // ---- GEMM2: hid(64x128) @ W2(128x128) -> m ----
    f32x4 acc2[4][2] = {};
#pragma unroll
    for (int kk = 0; kk < 4; ++kk) {
        const short8 bf0 = w2p[(kk * 8 + wave * 2 + 0) * 64 + lane];
        const short8 bf1 = w2p[(kk * 8 + wave * 2 + 1) * 64 + lane];
#pragma unroll
        for (int mt = 0; mt < 4; ++mt) {
            const int r = mt * 16 + lr;
            const short8 af = *(const short8*)(smem + r * 256 + ((kk * 64 + lq * 16) ^ ((r & 7) << 4)));
            acc2[mt][0] = __builtin_amdgcn_mfma_f32_16x16x32_bf16(af, bf0, acc2[mt][0], 0, 0, 0);
            acc2[mt][1] = __builtin_amdgcn_mfma_f32_16x16x32_bf16(af, bf1, acc2[mt][1], 0, 0, 0);
        }
    }
    // ---- epilogue 2: m = silu(acc2 + b2) -> LDS m region (disjoint from hid) ----
    {
        const int c0 = wave * 32 + lr, c1 = c0 + 16;
        const float bb0 = b2[c0], bb1 = b2[c1];
#pragma unroll
        for (int mt = 0; mt < 4; ++mt)
#pragma unroll
            for (int reg = 0; reg < 4; ++reg) {
                const int r = mt * 16 + lq * 4 + reg;
                const int swz = (r & 7) << 4;
                const float v0 = silu_f(acc2[mt][0][reg] + bb0);
                const float v1 = silu_f(acc2[mt][1][reg] + bb1);
                *(unsigned short*)(smem + 16384 + r * 256 + ((c0 * 2) ^ swz)) = f2bf(v0);
                *(unsigned short*)(smem + 16384 + r * 256 + ((c1 * 2) ^ swz)) = f2bf(v1);
            }
    }
    __syncthreads();

    // ---- GEMM3: m(64x128) @ cW1(128x128) ----
    f32x4 acc3[4][2] = {};
#pragma unroll
    for (int kk = 0; kk < 4; ++kk) {
        const short8 bf0 = cw1p[(kk * 8 + wave * 2 + 0) * 64 + lane];
        const short8 bf1 = cw1p[(kk * 8 + wave * 2 + 1) * 64 + lane];
#pragma unroll
        for (int mt = 0; mt < 4; ++mt) {
            const int r = mt * 16 + lr;
            const short8 af = *(const short8*)(smem + 16384 + r * 256 + ((kk * 64 + lq * 16) ^ ((r & 7) << 4)));
            acc3[mt][0] = __builtin_amdgcn_mfma_f32_16x16x32_bf16(af, bf0, acc3[mt][0], 0, 0, 0);
            acc3[mt][1] = __builtin_amdgcn_mfma_f32_16x16x32_bf16(af, bf1, acc3[mt][1], 0, 0, 0);
        }
    }
    // ---- m -> global (bf16, coalesced from LDS), aliased over edge_attr rows ----
#pragma unroll
    for (int i = 0; i < 4; ++i) {
        const int g = t * 4 + i;
        const int row = g >> 4, sl = g & 15;
        const uint4 v = *(const uint4*)(smem + 16384 + row * 256 + ((sl * 16) ^ ((row & 7) << 4)));
        *(uint4*)(ea + (size_t)(ebase + row) * EA_STRIDE + sl * 8) = v;
    }
    // ---- epilogue 3: c = sum_col silu(acc3 + cb1) * cw2 ----
    {
        const int c0 = wave * 32 + lr, c1 = c0 + 16;
        const float bb0 = cb1[c0], bb1 = cb1[c1];
        const float wc0 = cw2[c0], wc1 = cw2[c1];
#pragma unroll
        for (int mt = 0; mt < 4; ++mt)
#pragma unroll
            for (int reg = 0; reg < 4; ++reg) {
                float p = silu_f(acc3[mt][0][reg] + bb0) * wc0
                        + silu_f(acc3[mt][1][reg] + bb1) * wc1;
                p += __shfl_xor(p, 1);
                p += __shfl_xor(p, 2);
                p += __shfl_xor(p, 4);
                p += __shfl_xor(p, 8);
                if (lr == 0) red[wave * 64 + mt * 16 + lq * 4 + reg] = p;
            }
    }
    __syncthreads();
    if (t < 64) c_out[ebase + t] = red[t] + red[64 + t] + red[128 + t] + red[192 + t];
}

// ---------------- per-node: aggregate m (bf16), node MLP (f32, residual), coord update
__global__ __launch_bounds__(128) void node_kernel(
    float* __restrict__ h, const float* __restrict__ x_in, float* __restrict__ x_out,
    const unsigned short* __restrict__ m, const float* __restrict__ c_ws,
    const int* __restrict__ ecol,
    const float* __restrict__ nW1, const float* __restrict__ nb1,
    const float* __restrict__ nW2, const float* __restrict__ nb2,
    unsigned short* __restrict__ h_bf,
    float* __restrict__ out, const int write_out)
{
    const int n = blockIdx.x;
    const int o = threadIdx.x;
    __shared__ float nin[2 * HID];
    __shared__ float hidl[HID];
    const float hval = h[n * HID + o];
    const size_t mbase = (size_t)n * DEG * EA_STRIDE;
    float agg = 0.0f;
    for (int k = 0; k < DEG; ++k) agg += bf2f(m[mbase + (size_t)k * EA_STRIDE + o]);
    nin[o]       = hval;
    nin[HID + o] = agg;
    __syncthreads();
    float acc = nb1[o];
    for (int k = 0; k < 2 * HID; ++k) acc += nin[k] * nW1[k * HID + o];
    hidl[o] = silu_f(acc);
    __syncthreads();
    acc = nb2[o];
    for (int k = 0; k < HID; ++k) acc += hidl[k] * nW2[k * HID + o];
    const float hnew = hval + acc;
    h[n * HID + o] = hnew;
    h_bf[n * HID + o] = f2bf(hnew);
    if (write_out) out[n * HID + o] = hnew;

    if (o < 3) {
        const float xi = x_in[n * 3 + o];
        float s = 0.0f;
        const int eb = n * DEG;
        for (int k = 0; k < DEG; ++k) {
            const int col = ecol[eb + k];
            s += c_ws[eb + k] * (xi - x_in[col * 3 + o]);
        }
        x_out[n * 3 + o] = xi + s * (1.0f / DEG);
    }
}

extern "C" void kernel_launch(void* const* d_in, const int* in_sizes, int n_in,
                              void* d_out, int out_size, void* d_ws, size_t ws_size,
                              hipStream_t stream)
{
    const float* h_in  = (const float*)d_in[0];
    const float* x_in  = (const float*)d_in[1];
    const int*   erow  = (const int*)d_in[2];
    const int*   ecol  = (const int*)d_in[3];
    const float* ea0   = (const float*)d_in[4];
    const float* emb_w = (const float*)d_in[5];
    const float* emb_b = (const float*)d_in[6];
    const float* eW1   = (const float*)d_in[7];
    const float* eB1   = (const float*)d_in[8];
    const float* eW2   = (const float*)d_in[9];
    const float* eB2   = (const float*)d_in[10];
    const float* nW1   = (const float*)d_in[11];
    const float* nB1   = (const float*)d_in[12];
    const float* nW2   = (const float*)d_in[13];
    const float* nB2   = (const float*)d_in[14];
    const float* cW1   = (const float*)d_in[15];
    const float* cB1   = (const float*)d_in[16];
    const float* cW2   = (const float*)d_in[17];
    float* out = (float*)d_out;

    // bf16 edge features live aliased over the f32 edge_attr input, one bf16
    // row (256 B used of 512 B) per f32 row — byte ranges coincide per edge,
    // so in-place conversion at layer 0 is block-local (no cross-block race).
    unsigned short* ea_bf = (unsigned short*)d_in[4];

    // workspace carve (≈2.8 MB)
    char* w = (char*)d_ws;
    float* h_ws = (float*)w;            w += (size_t)NNODES * HID * 4;
    unsigned short* h_bf = (unsigned short*)w; w += (size_t)NNODES * HID * 2;
    float* x_a  = (float*)w;            w += (size_t)NNODES * 3 * 4 + 8;
    float* x_b  = (float*)w;            w += (size_t)NNODES * 3 * 4 + 8;
    float* c_ws = (float*)w;            w += (size_t)NEDGES * 4;
    unsigned short* w1p  = (unsigned short*)w; w += (size_t)NLAYER * 12 * 8 * 64 * 8 * 2;
    unsigned short* w2p  = (unsigned short*)w; w += (size_t)NLAYER * 4 * 8 * 64 * 8 * 2;
    unsigned short* cw1p = (unsigned short*)w; w += (size_t)NLAYER * 4 * 8 * 64 * 8 * 2;

    // weight packing (every launch; ws is re-poisoned each call)
    pack_w_kernel<<<NLAYER * 12 * 8, 64, 0, stream>>>(eW1, w1p, 12, K1 * HID, 1);
    pack_w_kernel<<<NLAYER * 4 * 8, 64, 0, stream>>>(eW2, w2p, 4, HID * HID, 0);
    pack_w_kernel<<<NLAYER * 4 * 8, 64, 0, stream>>>(cW1, cw1p, 4, HID * HID, 0);

    embed_kernel<<<NNODES, HID, 0, stream>>>(h_in, emb_w, emb_b, h_ws, h_bf, x_in, x_a);

    float* xc = x_a;
    float* xn = x_b;
    for (int i = 0; i < NLAYER; ++i) {
        edge_mfma_kernel<<<EBLOCKS, 256, 0, stream>>>(
            h_bf, xc, erow, ecol, ea0, ea_bf, (i == 0) ? 1 : 0,
            (const short8*)(w1p + (size_t)i * 12 * 8 * 64 * 8), eB1 + i * HID,
            eW1 + ((size_t)i * K1 + 256) * HID,
            (const short8*)(w2p + (size_t)i * 4 * 8 * 64 * 8), eB2 + i * HID,
            (const short8*)(cw1p + (size_t)i * 4 * 8 * 64 * 8), cB1 + i * HID,
            cW2 + (size_t)i * HID, c_ws);
        node_kernel<<<NNODES, HID, 0, stream>>>(
            h_ws, xc, xn, ea_bf, c_ws, ecol,
            nW1 + (size_t)i * 2 * HID * HID, nB1 + i * HID,
            nW2 + (size_t)i * HID * HID, nB2 + i * HID,
            h_bf, out, (i == NLAYER - 1) ? 1 : 0);
        float* tmp = xc; xc = xn; xn = tmp;
    }
}

// Round 4
// 369.398 us; speedup vs baseline: 13.0931x; 1.3351x over previous
//
#include <hip/hip_runtime.h>
#include <cstdint>
#include <cstddef>

#define HID    128
#define K1     385
#define NLAYER 4
#define NNODES 2048
#define NEDGES 129024
#define DEG    63
#define EPB    64               // edges per block
#define EBLOCKS (NEDGES / EPB)  // 2016
#define EA_STRIDE 256           // shorts per edge row aliased over f32 edge_attr row
#define NPB    32               // nodes per node-kernel block
#define NBLOCKS (NNODES / NPB)  // 64

// edge-kernel LDS byte map
#define EIN_STRIDE 512          // 256 bf16 per row
#define MBASE   16384
#define REDBASE 32768
#define RADBASE 34816
#define HR1BASE 35072
#define ELDS    36096

typedef __attribute__((ext_vector_type(8))) short short8;
typedef __attribute__((ext_vector_type(4))) float f32x4;

__device__ __forceinline__ unsigned short f2bf(float f) {
    unsigned int u = __builtin_bit_cast(unsigned int, f);
    unsigned int r = u + 0x7fffu + ((u >> 16) & 1u);
    return (unsigned short)(r >> 16);
}
__device__ __forceinline__ float bf2f(unsigned short h) {
    unsigned int u = ((unsigned int)h) << 16;
    return __builtin_bit_cast(float, u);
}
__device__ __forceinline__ float silu_f(float v) {
    return v / (1.0f + __expf(-v));
}

// row-major f32 (K x 128) -> fragment-linear bf16.
// mode 0: ka = kd. mode 1 (edge W1 minus h_row/radial): ka = 128 + kd + (kd>=128)
__global__ __launch_bounds__(64) void pack_w_kernel(
    const float* __restrict__ src, unsigned short* __restrict__ dst,
    const int KK, const int layerStride, const int mode)
{
    int b = blockIdx.x;
    const int tn = b & 7; b >>= 3;
    const int kk = b % KK;
    const int layer = b / KK;
    const int lane = threadIdx.x, lq = lane >> 4, lr = lane & 15;
    const float* s = src + (size_t)layer * layerStride;
    unsigned short* d = dst + (size_t)layer * (KK * 8 * 64 * 8)
                            + ((size_t)(kk * 8 + tn) * 64 + lane) * 8;
#pragma unroll
    for (int j = 0; j < 8; ++j) {
        const int kd = kk * 32 + lq * 8 + j;
        const int ka = mode ? (128 + kd + (kd >= 128 ? 1 : 0)) : kd;
        d[j] = f2bf(s[(size_t)ka * HID + tn * 16 + lr]);
    }
}

// embed + hr1(layer0) + agg zero + x copy
__global__ __launch_bounds__(128) void embed_kernel(
    const float* __restrict__ h_in, const float* __restrict__ emb_w,
    const float* __restrict__ emb_b, const float* __restrict__ eW1,
    float* __restrict__ h_ws, unsigned short* __restrict__ h_bf,
    float* __restrict__ hr1, float* __restrict__ agg,
    const float* __restrict__ x_in, float* __restrict__ x_a)
{
    const int n = blockIdx.x;
    const int o = threadIdx.x;
    __shared__ float hin[32];
    __shared__ float hrow[HID];
    if (o < 32) hin[o] = h_in[n * 32 + o];
    __syncthreads();
    float acc = emb_b[o];
#pragma unroll
    for (int k = 0; k < 32; ++k) acc += hin[k] * emb_w[k * HID + o];
    h_ws[n * HID + o] = acc;
    h_bf[n * HID + o] = f2bf(acc);
    hrow[o] = acc;
    agg[n * HID + o] = 0.0f;
    if (o < 3) x_a[n * 3 + o] = x_in[n * 3 + o];
    __syncthreads();
    float a2 = 0.0f;
    for (int k = 0; k < HID; ++k) a2 += hrow[k] * eW1[k * HID + o];
    hr1[n * HID + o] = a2;
}

// fused edge kernel: [h_col|ea] GEMM(K=256) + h_row/radial rank-1 -> silu
// -> GEMM2 -> silu = m (store + per-node agg atomics) -> GEMM3 -> coord scalar
__global__ __launch_bounds__(512, 6) void edge_mfma_kernel(
    const unsigned short* __restrict__ h_bf, const float* __restrict__ x,
    const float* __restrict__ ea_f32, unsigned short* __restrict__ ea,
    const int first_layer, const float* __restrict__ hr1,
    const short8* __restrict__ w1p, const float* __restrict__ b1, const float* __restrict__ w256,
    const short8* __restrict__ w2p, const float* __restrict__ b2,
    const short8* __restrict__ cw1p, const float* __restrict__ cb1, const float* __restrict__ cw2,
    float* __restrict__ c_out, float* __restrict__ agg)
{
    __shared__ __align__(16) char smem[ELDS];
    float* red    = (float*)(smem + REDBASE);
    float* radial = (float*)(smem + RADBASE);
    float* hr1s   = (float*)(smem + HR1BASE);
    const int t = threadIdx.x;
    const int w = t >> 6, lane = t & 63, lq = lane >> 4, lr = lane & 15;
    const int ebase = blockIdx.x * EPB;
    const int n0 = ebase / DEG;                 // first node of block
    const int esplit = DEG * (n0 + 1) - ebase;  // rows >= esplit belong to n0+1

    // ---- staging: 16 lanes cover one row's 16 slots (conflict-free, coalesced)
    {
        const int s = t & 15, g = t >> 4;       // g in 0..31
#pragma unroll
        for (int j = 0; j < 2; ++j) {
            const int r = g + j * 32;
            const int e = ebase + r;
            const int row = n0 + (r >= esplit ? 1 : 0);
            const int jj = e - row * DEG;
            const int rl = row & 63;
            const int col = (row & ~63) + jj + (jj >= rl ? 1 : 0);
            const int swz = (r & 7) << 4;
            // h_col segment (slots 0..15)
            *(uint4*)(smem + r * EIN_STRIDE + ((s * 16) ^ swz)) =
                *(const uint4*)(h_bf + (size_t)col * HID + s * 8);
            // edge_attr segment (slots 16..31)
            uint4 v;
            if (first_layer) {
                const float4* ef = (const float4*)(ea_f32 + (size_t)e * HID);
                const float4 f0 = ef[s * 2], f1 = ef[s * 2 + 1];
                v.x = (unsigned)f2bf(f0.x) | ((unsigned)f2bf(f0.y) << 16);
                v.y = (unsigned)f2bf(f0.z) | ((unsigned)f2bf(f0.w) << 16);
                v.z = (unsigned)f2bf(f1.x) | ((unsigned)f2bf(f1.y) << 16);
                v.w = (unsigned)f2bf(f1.z) | ((unsigned)f2bf(f1.w) << 16);
            } else {
                v = *(const uint4*)(ea + (size_t)e * EA_STRIDE + s * 8);
            }
            *(uint4*)(smem + r * EIN_STRIDE + (((s + 16) * 16) ^ swz)) = v;
            if (s == 0) {
                const float dx = x[row * 3 + 0] - x[col * 3 + 0];
                const float dy = x[row * 3 + 1] - x[col * 3 + 1];
                const float dz = x[row * 3 + 2] - x[col * 3 + 2];
                radial[r] = dx * dx + dy * dy + dz * dz;
            }
        }
        if (t < 256) hr1s[t] = hr1[(size_t)(n0 + (t >> 7)) * HID + (t & 127)];
    }
    __syncthreads();

    const int c0 = w * 16 + lr;

    // ---- GEMM1: einA(64x256) @ W1' ; wave w owns cols [w*16, w*16+16)
    f32x4 acc1[4] = {};
#pragma unroll
    for (int kk = 0; kk < 8; ++kk) {
        const short8 bf = w1p[(kk * 8 + w) * 64 + lane];
#pragma unroll
        for (int mt = 0; mt < 4; ++mt) {
            const int r = mt * 16 + lr;
            const short8 af = *(const short8*)(smem + r * EIN_STRIDE +
                                ((kk * 64 + lq * 16) ^ ((r & 7) << 4)));
            acc1[mt] = __builtin_amdgcn_mfma_f32_16x16x32_bf16(af, bf, acc1[mt], 0, 0, 0);
        }
    }
    __syncthreads();   // einA dead; hid overlays base 0

    // ---- epilogue 1: hid = silu(acc + b1 + radial*w256 + hr1[node])
    {
        const float bb = b1[c0], ww = w256[c0];
        const float ha = hr1s[c0], hb = hr1s[128 + c0];
#pragma unroll
        for (int mt = 0; mt < 4; ++mt)
#pragma unroll
            for (int reg = 0; reg < 4; ++reg) {
                const int r = mt * 16 + lq * 4 + reg;
                const float v = silu_f(acc1[mt][reg] + bb + radial[r] * ww +
                                       (r < esplit ? ha : hb));
                *(unsigned short*)(smem + r * 256 + ((c0 * 2) ^ ((r & 7) << 4))) = f2bf(v);
            }
    }
    __syncthreads();

    // ---- GEMM2: hid(64x128) @ W2
    f32x4 acc2[4] = {};
#pragma unroll
    for (int kk = 0; kk < 4; ++kk) {
        const short8 bf = w2p[(kk * 8 + w) * 64 + lane];
#pragma unroll
        for (int mt = 0; mt < 4; ++mt) {
            const int r = mt * 16 + lr;
            const short8 af = *(const short8*)(smem + r * 256 +
                                ((kk * 64 + lq * 16) ^ ((r & 7) << 4)));
            acc2[mt] = __builtin_amdgcn_mfma_f32_16x16x32_bf16(af, bf, acc2[mt], 0, 0, 0);
        }
    }
    // ---- epilogue 2: m = silu(acc2+b2) -> LDS + per-node column sums (agg)
    {
        const float bb = b2[c0];
        float s0 = 0.0f, s1 = 0.0f;
#pragma unroll
        for (int mt = 0; mt < 4; ++mt)
#pragma unroll
            for (int reg = 0; reg < 4; ++reg) {
                const int r = mt * 16 + lq * 4 + reg;
                const float v = silu_f(acc2[mt][reg] + bb);
                if (r < esplit) s0 += v; else s1 += v;
                *(unsigned short*)(smem + MBASE + r * 256 + ((c0 * 2) ^ ((r & 7) << 4))) = f2bf(v);
            }
        s0 += __shfl_xor(s0, 16); s0 += __shfl_xor(s0, 32);
        s1 += __shfl_xor(s1, 16); s1 += __shfl_xor(s1, 32);
        if (lane < 16) {
            atomicAdd(&agg[(size_t)n0 * HID + c0], s0);
            atomicAdd(&agg[(size_t)(n0 + 1) * HID + c0], s1);
        }
    }
    __syncthreads();

    // ---- GEMM3: m(64x128) @ cW1
    f32x4 acc3[4] = {};
#pragma unroll
    for (int kk = 0; kk < 4; ++kk) {
        const short8 bf = cw1p[(kk * 8 + w) * 64 + lane];
#pragma unroll
        for (int mt = 0; mt < 4; ++mt) {
            const int r = mt * 16 + lr;
            const short8 af = *(const short8*)(smem + MBASE + r * 256 +
                                ((kk * 64 + lq * 16) ^ ((r & 7) << 4)));
            acc3[mt] = __builtin_amdgcn_mfma_f32_16x16x32_bf16(af, bf, acc3[mt], 0, 0, 0);
        }
    }
    // ---- m -> global (bf16, row-contiguous from LDS)
    {
        const int s = t & 15, g = t >> 4;
#pragma unroll
        for (int j = 0; j < 2; ++j) {
            const int r = g + j * 32;
            const uint4 v = *(const uint4*)(smem + MBASE + r * 256 +
                                            ((s * 16) ^ ((r & 7) << 4)));
            *(uint4*)(ea + (size_t)(ebase + r) * EA_STRIDE + s * 8) = v;
        }
    }
    // ---- epilogue 3: c_e = sum_col silu(acc3+cb1)*cw2
    {
        const float cb = cb1[c0], wc = cw2[c0];
#pragma unroll
        for (int mt = 0; mt < 4; ++mt)
#pragma unroll
            for (int reg = 0; reg < 4; ++reg) {
                float p = silu_f(acc3[mt][reg] + cb) * wc;
                p += __shfl_xor(p, 1);
                p += __shfl_xor(p, 2);
                p += __shfl_xor(p, 4);
                p += __shfl_xor(p, 8);
                if (lr == 0) red[w * 64 + mt * 16 + lq * 4 + reg] = p;
            }
    }
    __syncthreads();
    if (t < 64) {
        float s = 0.0f;
#pragma unroll
        for (int ww = 0; ww < 8; ++ww) s += red[ww * 64 + t];
        c_out[ebase + t] = s;
    }
}

// node kernel: [h|agg] MLP (MFMA, residual) + agg re-zero + coord update
// + next-layer hr1 = hnew @ W1a
__global__ __launch_bounds__(512, 4) void node_mfma_kernel(
    float* __restrict__ h_ws, unsigned short* __restrict__ h_bf,
    float* __restrict__ agg,
    const short8* __restrict__ nw1p, const float* __restrict__ nb1,
    const short8* __restrict__ nw2p, const float* __restrict__ nb2,
    const short8* __restrict__ w1a_next, float* __restrict__ hr1,
    const float* __restrict__ x_in, float* __restrict__ x_out,
    const float* __restrict__ c_ws,
    float* __restrict__ out, const int write_out, const int do_coord)
{
    __shared__ __align__(16) char smem[32768];  // nin[32][512B] | hid@16384 | hnew@24576
    const int t = threadIdx.x;
    const int w = t >> 6, lane = t & 63, lq = lane >> 4, lr = lane & 15;
    const int nb = blockIdx.x * NPB;

    // ---- stage nin = [h | agg], zero agg
    {
        const int s = t & 15, g = t >> 4;       // g = row 0..31
        const int node = nb + g;
        const int swz = (g & 7) << 4;
        *(uint4*)(smem + g * 512 + ((s * 16) ^ swz)) =
            *(const uint4*)(h_bf + (size_t)node * HID + s * 8);
        float4* agg4 = (float4*)(agg + (size_t)node * HID);
        const float4 a0 = agg4[s * 2], a1 = agg4[s * 2 + 1];
        agg4[s * 2] = float4{0, 0, 0, 0};
        agg4[s * 2 + 1] = float4{0, 0, 0, 0};
        uint4 v;
        v.x = (unsigned)f2bf(a0.x) | ((unsigned)f2bf(a0.y) << 16);
        v.y = (unsigned)f2bf(a0.z) | ((unsigned)f2bf(a0.w) << 16);
        v.z = (unsigned)f2bf(a1.x) | ((unsigned)f2bf(a1.y) << 16);
        v.w = (unsigned)f2bf(a1.z) | ((unsigned)f2bf(a1.w) << 16);
        *(uint4*)(smem + g * 512 + (((s + 16) * 16) ^ swz)) = v;
    }
    __syncthreads();

    const int c0 = w * 16 + lr;

    // ---- GEMM1: nin(32x256) @ nW1
    f32x4 acc1[2] = {};
#pragma unroll
    for (int kk = 0; kk < 8; ++kk) {
        const short8 bf = nw1p[(kk * 8 + w) * 64 + lane];
#pragma unroll
        for (int mt = 0; mt < 2; ++mt) {
            const int r = mt * 16 + lr;
            const short8 af = *(const short8*)(smem + r * 512 +
                                ((kk * 64 + lq * 16) ^ ((r & 7) << 4)));
            acc1[mt] = __builtin_amdgcn_mfma_f32_16x16x32_bf16(af, bf, acc1[mt], 0, 0, 0);
        }
    }
    __syncthreads();
    // ---- epilogue 1 -> hid
    {
        const float bb = nb1[c0];
#pragma unroll
        for (int mt = 0; mt < 2; ++mt)
#pragma unroll
            for (int reg = 0; reg < 4; ++reg) {
                const int r = mt * 16 + lq * 4 + reg;
                const float v = silu_f(acc1[mt][reg] + bb);
                *(unsigned short*)(smem + 16384 + r * 256 + ((c0 * 2) ^ ((r & 7) << 4))) = f2bf(v);
            }
    }
    __syncthreads();
    // ---- GEMM2: hid(32x128) @ nW2
    f32x4 acc2[2] = {};
#pragma unroll
    for (int kk = 0; kk < 4; ++kk) {
        const short8 bf = nw2p[(kk * 8 + w) * 64 + lane];
#pragma unroll
        for (int mt = 0; mt < 2; ++mt) {
            const int r = mt * 16 + lr;
            const short8 af = *(const short8*)(smem + 16384 + r * 256 +
                                ((kk * 64 + lq * 16) ^ ((r & 7) << 4)));
            acc2[mt] = __builtin_amdgcn_mfma_f32_16x16x32_bf16(af, bf, acc2[mt], 0, 0, 0);
        }
    }
    // ---- epilogue 2: residual, write h (f32/bf16/out), stage hnew for hr1 GEMM
    {
        const float bb = nb2[c0];
#pragma unroll
        for (int mt = 0; mt < 2; ++mt)
#pragma unroll
            for (int reg = 0; reg < 4; ++reg) {
                const int r = mt * 16 + lq * 4 + reg;
                const size_t gi = (size_t)(nb + r) * HID + c0;
                const float hnew = h_ws[gi] + acc2[mt][reg] + bb;
                h_ws[gi] = hnew;
                h_bf[gi] = f2bf(hnew);
                if (write_out) out[gi] = hnew;
                *(unsigned short*)(smem + 24576 + r * 256 + ((c0 * 2) ^ ((r & 7) << 4))) = f2bf(hnew);
            }
    }
    __syncthreads();
    // ---- hr1 for next layer: hnew(32x128) @ W1a_next
    if (w1a_next) {
        f32x4 acch[2] = {};
#pragma unroll
        for (int kk = 0; kk < 4; ++kk) {
            const short8 bf = w1a_next[(kk * 8 + w) * 64 + lane];
#pragma unroll
            for (int mt = 0; mt < 2; ++mt) {
                const int r = mt * 16 + lr;
                const short8 af = *(const short8*)(smem + 24576 + r * 256 +
                                    ((kk * 64 + lq * 16) ^ ((r & 7) << 4)));
                acch[mt] = __builtin_amdgcn_mfma_f32_16x16x32_bf16(af, bf, acch[mt], 0, 0, 0);
            }
        }
#pragma unroll
        for (int mt = 0; mt < 2; ++mt)
#pragma unroll
            for (int reg = 0; reg < 4; ++reg) {
                const int r = mt * 16 + lq * 4 + reg;
                hr1[(size_t)(nb + r) * HID + c0] = acch[mt][reg];
            }
    }
    // ---- coordinate update: x_out = x_in + sum_e c_e*(x_i - x_col)/63
    if (do_coord) {
        const int nl = t >> 4, sub = t & 15;
        const int n = nb + nl;
        const int rl = n & 63, base = n & ~63;
        const float xi0 = x_in[n * 3 + 0], xi1 = x_in[n * 3 + 1], xi2 = x_in[n * 3 + 2];
        float p0 = 0, p1 = 0, p2 = 0;
#pragma unroll
        for (int kk = 0; kk < 4; ++kk) {
            const int k = sub + kk * 16;
            if (k < DEG) {
                const int e = n * DEG + k;
                const int col = base + k + (k >= rl ? 1 : 0);
                const float c = c_ws[e];
                p0 += c * (xi0 - x_in[col * 3 + 0]);
                p1 += c * (xi1 - x_in[col * 3 + 1]);
                p2 += c * (xi2 - x_in[col * 3 + 2]);
            }
        }
#pragma unroll
        for (int off = 1; off < 16; off <<= 1) {
            p0 += __shfl_xor(p0, off);
            p1 += __shfl_xor(p1, off);
            p2 += __shfl_xor(p2, off);
        }
        if (sub == 0) {
            const float inv = 1.0f / DEG;
            x_out[n * 3 + 0] = xi0 + p0 * inv;
            x_out[n * 3 + 1] = xi1 + p1 * inv;
            x_out[n * 3 + 2] = xi2 + p2 * inv;
        }
    }
}

extern "C" void kernel_launch(void* const* d_in, const int* in_sizes, int n_in,
                              void* d_out, int out_size, void* d_ws, size_t ws_size,
                              hipStream_t stream)
{
    const float* h_in  = (const float*)d_in[0];
    const float* x_in  = (const float*)d_in[1];
    const float* ea0   = (const float*)d_in[4];
    const float* emb_w = (const float*)d_in[5];
    const float* emb_b = (const float*)d_in[6];
    const float* eW1   = (const float*)d_in[7];
    const float* eB1   = (const float*)d_in[8];
    const float* eW2   = (const float*)d_in[9];
    const float* eB2   = (const float*)d_in[10];
    const float* nW1   = (const float*)d_in[11];
    const float* nB1   = (const float*)d_in[12];
    const float* nW2   = (const float*)d_in[13];
    const float* nB2   = (const float*)d_in[14];
    const float* cW1   = (const float*)d_in[15];
    const float* cB1   = (const float*)d_in[16];
    const float* cW2   = (const float*)d_in[17];
    float* out = (float*)d_out;

    // bf16 edge features aliased over f32 edge_attr (256B used of each 512B row;
    // per-edge byte ranges coincide -> block-local in-place conversion, no race)
    unsigned short* ea_bf = (unsigned short*)d_in[4];

    char* p = (char*)d_ws;
    float* h_ws = (float*)p;                    p += (size_t)NNODES * HID * 4;
    unsigned short* h_bf = (unsigned short*)p;  p += (size_t)NNODES * HID * 2;
    float* agg  = (float*)p;                    p += (size_t)NNODES * HID * 4;
    float* hr1  = (float*)p;                    p += (size_t)NNODES * HID * 4;
    float* x_a  = (float*)p;                    p += NNODES * 3 * 4 + 16;
    float* x_b  = (float*)p;                    p += NNODES * 3 * 4 + 16;
    float* c_ws = (float*)p;                    p += (size_t)NEDGES * 4;
    unsigned short* w1p  = (unsigned short*)p;  p += (size_t)NLAYER * 8 * 8 * 64 * 8 * 2;
    unsigned short* w1a  = (unsigned short*)p;  p += (size_t)NLAYER * 4 * 8 * 64 * 8 * 2;
    unsigned short* w2p  = (unsigned short*)p;  p += (size_t)NLAYER * 4 * 8 * 64 * 8 * 2;
    unsigned short* cw1p = (unsigned short*)p;  p += (size_t)NLAYER * 4 * 8 * 64 * 8 * 2;
    unsigned short* nw1p = (unsigned short*)p;  p += (size_t)NLAYER * 8 * 8 * 64 * 8 * 2;
    unsigned short* nw2p = (unsigned short*)p;  p += (size_t)NLAYER * 4 * 8 * 64 * 8 * 2;

    const int SL8 = 8 * 8 * 64 * 8;   // shorts per layer, KK=8
    const int SL4 = 4 * 8 * 64 * 8;   // shorts per layer, KK=4

    pack_w_kernel<<<NLAYER * 8 * 8, 64, 0, stream>>>(eW1, w1p, 8, K1 * HID, 1);
    pack_w_kernel<<<NLAYER * 4 * 8, 64, 0, stream>>>(eW1, w1a, 4, K1 * HID, 0);
    pack_w_kernel<<<NLAYER * 4 * 8, 64, 0, stream>>>(eW2, w2p, 4, HID * HID, 0);
    pack_w_kernel<<<NLAYER * 4 * 8, 64, 0, stream>>>(cW1, cw1p, 4, HID * HID, 0);
    pack_w_kernel<<<NLAYER * 8 * 8, 64, 0, stream>>>(nW1, nw1p, 8, 2 * HID * HID, 0);
    pack_w_kernel<<<NLAYER * 4 * 8, 64, 0, stream>>>(nW2, nw2p, 4, HID * HID, 0);

    embed_kernel<<<NNODES, HID, 0, stream>>>(h_in, emb_w, emb_b, eW1,
                                             h_ws, h_bf, hr1, agg, x_in, x_a);

    float* xc = x_a;
    float* xn = x_b;
    for (int i = 0; i < NLAYER; ++i) {
        edge_mfma_kernel<<<EBLOCKS, 512, 0, stream>>>(
            h_bf, xc, ea0, ea_bf, (i == 0) ? 1 : 0, hr1,
            (const short8*)(w1p + (size_t)i * SL8), eB1 + i * HID,
            eW1 + ((size_t)i * K1 + 256) * HID,
            (const short8*)(w2p + (size_t)i * SL4), eB2 + i * HID,
            (const short8*)(cw1p + (size_t)i * SL4), cB1 + i * HID,
            cW2 + (size_t)i * HID, c_ws, agg);
        node_mfma_kernel<<<NBLOCKS, 512, 0, stream>>>(
            h_ws, h_bf, agg,
            (const short8*)(nw1p + (size_t)i * SL8), nB1 + i * HID,
            (const short8*)(nw2p + (size_t)i * SL4), nB2 + i * HID,
            (i < NLAYER - 1) ? (const short8*)(w1a + (size_t)(i + 1) * SL4) : (const short8*)nullptr,
            hr1, xc, xn, c_ws,
            out, (i == NLAYER - 1) ? 1 : 0, (i < NLAYER - 1) ? 1 : 0);
        float* tmp = xc; xc = xn; xn = tmp;
    }
}

// Round 6
// 306.241 us; speedup vs baseline: 15.7933x; 1.2062x over previous
//
#include <hip/hip_runtime.h>
#include <cstdint>
#include <cstddef>

#define HID    128
#define K1     385
#define NLAYER 4
#define NNODES 2048
#define NEDGES 129024
#define DEG    63
#define EPB    64               // edges per block
#define EBLOCKS (NEDGES / EPB)  // 2016
#define EA_STRIDE 256           // shorts per edge row aliased over f32 edge_attr row
#define NPB    16               // nodes per node-kernel block
#define NBLOCKS (NNODES / NPB)  // 128

// edge-kernel LDS byte map
#define EIN_STRIDE 512          // 256 bf16 per row
#define MBASE   16384
#define REDBASE 32768           // 128 f32
#define RADBASE 33280           // 64 f32
#define HR1BASE 33536           // 256 f32 (hr1b: hr1 + b1, 2 nodes)
#define CB1BASE 34560           // 128 f32
#define CW2BASE 35072           // 128 f32
#define ELDS    35584

typedef __attribute__((ext_vector_type(8))) short short8;
typedef __attribute__((ext_vector_type(4))) float f32x4;

__device__ __forceinline__ unsigned pkbf(float a, float b) {
    unsigned r;
    asm("v_cvt_pk_bf16_f32 %0, %1, %2" : "=v"(r) : "v"(a), "v"(b));
    return r;   // low16 = bf16(a), high16 = bf16(b), RNE
}
__device__ __forceinline__ unsigned short f2bf(float a) {
    return (unsigned short)pkbf(a, a);
}
__device__ __forceinline__ float silu_f(float v) {
    // v * rcp(1+exp(-v)) : raw v_rcp (1 ulp) instead of IEEE div sequence
    return v * __builtin_amdgcn_rcpf(1.0f + __expf(-v));
}

// ---- unified weight packer: row-major f32 (K x 128) -> fragment-linear bf16
// dst[((kk*8+tn)*64+lane)*8+j] = W[rowmap(kk*32+(lane>>4)*8+j)][tn*16+(lane&15)]
// segments (64-thread blocks): see kernel_launch
__global__ __launch_bounds__(64) void pack_all_kernel(
    const float* __restrict__ eW1, const float* __restrict__ eW2,
    const float* __restrict__ cW1, const float* __restrict__ nW1,
    const float* __restrict__ nW2,
    unsigned short* __restrict__ w1p, unsigned short* __restrict__ w1a,
    unsigned short* __restrict__ w2p, unsigned short* __restrict__ cw1p,
    unsigned short* __restrict__ nw1p, unsigned short* __restrict__ nw2p)
{
    int b = blockIdx.x;
    const float* src; unsigned short* dst; int KK, ls, mode;
    if (b < 256)      { src = eW1; dst = w1p;  KK = 8; ls = K1 * HID;      mode = 1; }
    else if (b < 384) { src = eW1; dst = w1a;  KK = 4; ls = K1 * HID;      mode = 0; b -= 256; }
    else if (b < 512) { src = eW2; dst = w2p;  KK = 4; ls = HID * HID;     mode = 0; b -= 384; }
    else if (b < 640) { src = cW1; dst = cw1p; KK = 4; ls = HID * HID;     mode = 0; b -= 512; }
    else if (b < 896) { src = nW1; dst = nw1p; KK = 8; ls = 2 * HID * HID; mode = 0; b -= 640; }
    else              { src = nW2; dst = nw2p; KK = 4; ls = HID * HID;     mode = 0; b -= 896; }
    const int tn = b & 7; b >>= 3;
    const int kk = b % KK;
    const int layer = b / KK;
    const int lane = threadIdx.x, lq = lane >> 4, lr = lane & 15;
    const float* s = src + (size_t)layer * ls;
    unsigned short* d = dst + (size_t)layer * (KK * 8 * 64 * 8)
                            + ((size_t)(kk * 8 + tn) * 64 + lane) * 8;
#pragma unroll
    for (int j = 0; j < 8; ++j) {
        const int kd = kk * 32 + lq * 8 + j;
        const int ka = mode ? (128 + kd + (kd >= 128 ? 1 : 0)) : kd;
        d[j] = f2bf(s[(size_t)ka * HID + tn * 16 + lr]);
    }
}

// embed + hr1b(layer0, incl. b1) + agg zero + x copy
__global__ __launch_bounds__(128) void embed_kernel(
    const float* __restrict__ h_in, const float* __restrict__ emb_w,
    const float* __restrict__ emb_b, const float* __restrict__ eW1,
    const float* __restrict__ eB1,
    float* __restrict__ h_ws, unsigned short* __restrict__ h_bf,
    float* __restrict__ hr1, float* __restrict__ agg,
    const float* __restrict__ x_in, float* __restrict__ x_a)
{
    const int n = blockIdx.x;
    const int o = threadIdx.x;
    __shared__ float hin[32];
    __shared__ float hrow[HID];
    if (o < 32) hin[o] = h_in[n * 32 + o];
    __syncthreads();
    float acc = emb_b[o];
#pragma unroll
    for (int k = 0; k < 32; ++k) acc += hin[k] * emb_w[k * HID + o];
    h_ws[n * HID + o] = acc;
    h_bf[n * HID + o] = f2bf(acc);
    hrow[o] = acc;
    agg[n * HID + o] = 0.0f;
    if (o < 3) x_a[n * 3 + o] = x_in[n * 3 + o];
    __syncthreads();
    float a2 = eB1[o];
    for (int k = 0; k < HID; ++k) a2 += hrow[k] * eW1[k * HID + o];
    hr1[n * HID + o] = a2;
}

// fused edge kernel
__global__ __launch_bounds__(512, 6) void edge_mfma_kernel(
    const unsigned short* __restrict__ h_bf, const float* __restrict__ x,
    const float* __restrict__ ea_f32, unsigned short* __restrict__ ea,
    const int first_layer, const float* __restrict__ hr1,
    const short8* __restrict__ w1p, const float* __restrict__ w256,
    const short8* __restrict__ w2p, const float* __restrict__ b2,
    const short8* __restrict__ cw1p, const float* __restrict__ cb1, const float* __restrict__ cw2,
    float* __restrict__ c_out, float* __restrict__ agg)
{
    __shared__ __align__(16) char smem[ELDS];
    float* red    = (float*)(smem + REDBASE);
    float* radial = (float*)(smem + RADBASE);
    float* hr1s   = (float*)(smem + HR1BASE);
    float* cb1s   = (float*)(smem + CB1BASE);
    float* cw2s   = (float*)(smem + CW2BASE);
    const int t = threadIdx.x;
    const int w = t >> 6, lane = t & 63, lq = lane >> 4, lr = lane & 15;
    const int ebase = blockIdx.x * EPB;
    const int n0 = ebase / DEG;
    const int esplit = DEG * (n0 + 1) - ebase;  // rows >= esplit belong to n0+1

    // ---- staging
    {
        const int s = t & 15, g = t >> 4;       // g in 0..31
#pragma unroll
        for (int j = 0; j < 2; ++j) {
            const int r = g + j * 32;
            const int e = ebase + r;
            const int row = n0 + (r >= esplit ? 1 : 0);
            const int jj = e - row * DEG;
            const int rl = row & 63;
            const int col = (row & ~63) + jj + (jj >= rl ? 1 : 0);
            const int swz = (r & 7) << 4;
            *(uint4*)(smem + r * EIN_STRIDE + ((s * 16) ^ swz)) =
                *(const uint4*)(h_bf + (size_t)col * HID + s * 8);
            uint4 v;
            if (first_layer) {
                const float4* ef = (const float4*)(ea_f32 + (size_t)e * HID);
                const float4 f0 = ef[s * 2], f1 = ef[s * 2 + 1];
                v.x = pkbf(f0.x, f0.y);
                v.y = pkbf(f0.z, f0.w);
                v.z = pkbf(f1.x, f1.y);
                v.w = pkbf(f1.z, f1.w);
            } else {
                v = *(const uint4*)(ea + (size_t)e * EA_STRIDE + s * 8);
            }
            *(uint4*)(smem + r * EIN_STRIDE + (((s + 16) * 16) ^ swz)) = v;
            if (s == 0) {
                const float dx = x[row * 3 + 0] - x[col * 3 + 0];
                const float dy = x[row * 3 + 1] - x[col * 3 + 1];
                const float dz = x[row * 3 + 2] - x[col * 3 + 2];
                radial[r] = dx * dx + dy * dy + dz * dz;
            }
        }
        if (t < 128) { cb1s[t] = cb1[t]; cw2s[t] = cw2[t]; }
        else if (t < 384) {
            const int i2 = t - 128;
            hr1s[i2] = hr1[(size_t)(n0 + (i2 >> 7)) * HID + (i2 & 127)];
        }
    }
    __syncthreads();

    const int c0 = w * 16 + lr;

    // ---- GEMM1: einA(64x256) @ W1' ; wave w owns cols [w*16, w*16+16)
    f32x4 acc1[4] = {};
#pragma unroll
    for (int kk = 0; kk < 8; ++kk) {
        const short8 bf = w1p[(kk * 8 + w) * 64 + lane];
#pragma unroll
        for (int mt = 0; mt < 4; ++mt) {
            const int r = mt * 16 + lr;
            const short8 af = *(const short8*)(smem + r * EIN_STRIDE +
                                ((kk * 64 + lq * 16) ^ ((r & 7) << 4)));
            acc1[mt] = __builtin_amdgcn_mfma_f32_16x16x32_bf16(af, bf, acc1[mt], 0, 0, 0);
        }
    }
    __syncthreads();   // einA dead; hid overlays base 0

    // ---- epilogue 1: hid = silu(acc + radial*w256 + hr1b[node])   (b1 in hr1b)
    {
        const float ww = w256[c0];
        const float ha = hr1s[c0], hb = hr1s[128 + c0];
#pragma unroll
        for (int mt = 0; mt < 4; ++mt)
#pragma unroll
            for (int reg = 0; reg < 4; ++reg) {
                const int r = mt * 16 + lq * 4 + reg;
                const float v = silu_f(acc1[mt][reg] + radial[r] * ww +
                                       (r < esplit ? ha : hb));
                *(unsigned short*)(smem + r * 256 + ((c0 * 2) ^ ((r & 7) << 4))) = f2bf(v);
            }
    }
    __syncthreads();

    // ---- GEMM2: hid(64x128) @ W2
    f32x4 acc2[4] = {};
#pragma unroll
    for (int kk = 0; kk < 4; ++kk) {
        const short8 bf = w2p[(kk * 8 + w) * 64 + lane];
#pragma unroll
        for (int mt = 0; mt < 4; ++mt) {
            const int r = mt * 16 + lr;
            const short8 af = *(const short8*)(smem + r * 256 +
                                ((kk * 64 + lq * 16) ^ ((r & 7) << 4)));
            acc2[mt] = __builtin_amdgcn_mfma_f32_16x16x32_bf16(af, bf, acc2[mt], 0, 0, 0);
        }
    }
    // ---- epilogue 2: m = silu(acc2+b2) -> LDS + per-node column sums (agg)
    {
        const float bb = b2[c0];
        float s0 = 0.0f, s1 = 0.0f;
#pragma unroll
        for (int mt = 0; mt < 4; ++mt)
#pragma unroll
            for (int reg = 0; reg < 4; ++reg) {
                const int r = mt * 16 + lq * 4 + reg;
                const float v = silu_f(acc2[mt][reg] + bb);
                if (r < esplit) s0 += v; else s1 += v;
                *(unsigned short*)(smem + MBASE + r * 256 + ((c0 * 2) ^ ((r & 7) << 4))) = f2bf(v);
            }
        s0 += __shfl_xor(s0, 16); s0 += __shfl_xor(s0, 32);
        s1 += __shfl_xor(s1, 16); s1 += __shfl_xor(s1, 32);
        if (lane < 16) {
            atomicAdd(&agg[(size_t)n0 * HID + c0], s0);
            atomicAdd(&agg[(size_t)(n0 + 1) * HID + c0], s1);
        }
    }
    __syncthreads();

    // ---- GEMM3 (transposed): C3[j2][e] = cW1^T(128x128) @ m^T
    // wave w: etile = w&3 (16 edges), jhalf = w>>2 (64 j2 rows)
    const int etile = w & 3, jhalf = w >> 2;
    f32x4 acc3[4] = {};
    {
        const int erow = etile * 16 + lr;
        const int eswz = (erow & 7) << 4;
#pragma unroll
        for (int kb = 0; kb < 4; ++kb) {
            const short8 mf = *(const short8*)(smem + MBASE + erow * 256 +
                                ((kb * 64 + lq * 16) ^ eswz));
#pragma unroll
            for (int jt = 0; jt < 4; ++jt) {
                const short8 af = cw1p[(kb * 8 + jhalf * 4 + jt) * 64 + lane];
                acc3[jt] = __builtin_amdgcn_mfma_f32_16x16x32_bf16(af, mf, acc3[jt], 0, 0, 0);
            }
        }
    }
    // ---- m -> global (bf16, row-contiguous from LDS)
    {
        const int s = t & 15, g = t >> 4;
#pragma unroll
        for (int j = 0; j < 2; ++j) {
            const int r = g + j * 32;
            const uint4 v = *(const uint4*)(smem + MBASE + r * 256 +
                                            ((s * 16) ^ ((r & 7) << 4)));
            *(uint4*)(ea + (size_t)(ebase + r) * EA_STRIDE + s * 8) = v;
        }
    }
    // ---- epilogue 3: per-lane dot over its 16 j2 rows, 2 shfl, 1 LDS write
    {
        float p = 0.0f;
#pragma unroll
        for (int jt = 0; jt < 4; ++jt)
#pragma unroll
            for (int reg = 0; reg < 4; ++reg) {
                const int j2 = jhalf * 64 + jt * 16 + lq * 4 + reg;
                p += silu_f(acc3[jt][reg] + cb1s[j2]) * cw2s[j2];
            }
        p += __shfl_xor(p, 16);
        p += __shfl_xor(p, 32);
        if (lane < 16) red[jhalf * 64 + etile * 16 + lane] = p;
    }
    __syncthreads();
    if (t < 64) c_out[ebase + t] = red[t] + red[64 + t];
}

// node kernel: [h|agg] MLP (MFMA, residual) + agg re-zero + coord update
// + next-layer hr1b = hnew @ W1a + b1_next
__global__ __launch_bounds__(512, 4) void node_mfma_kernel(
    float* __restrict__ h_ws, unsigned short* __restrict__ h_bf,
    float* __restrict__ agg,
    const short8* __restrict__ nw1p, const float* __restrict__ nb1,
    const short8* __restrict__ nw2p, const float* __restrict__ nb2,
    const short8* __restrict__ w1a_next, const float* __restrict__ b1_next,
    float* __restrict__ hr1,
    const float* __restrict__ x_in, float* __restrict__ x_out,
    const float* __restrict__ c_ws,
    float* __restrict__ out, const int write_out, const int do_coord)
{
    __shared__ __align__(16) char smem[16384];  // nin[16][512B] | hid@8192 | hnew@12288
    const int t = threadIdx.x;
    const int w = t >> 6, lane = t & 63, lq = lane >> 4, lr = lane & 15;
    const int nb = blockIdx.x * NPB;

    // ---- stage nin = [h | agg] (16 rows x 32 slots), zero agg
    {
        const int s = t & 31, g = t >> 5;       // g = row 0..15
        const int node = nb + g;
        const int swz = (g & 7) << 4;
        if (s < 16) {
            *(uint4*)(smem + g * 512 + ((s * 16) ^ swz)) =
                *(const uint4*)(h_bf + (size_t)node * HID + s * 8);
        } else {
            const int q = s - 16;
            float4* agg4 = (float4*)(agg + (size_t)node * HID);
            const float4 a0 = agg4[q * 2], a1 = agg4[q * 2 + 1];
            agg4[q * 2]     = float4{0, 0, 0, 0};
            agg4[q * 2 + 1] = float4{0, 0, 0, 0};
            uint4 v;
            v.x = pkbf(a0.x, a0.y);
            v.y = pkbf(a0.z, a0.w);
            v.z = pkbf(a1.x, a1.y);
            v.w = pkbf(a1.z, a1.w);
            *(uint4*)(smem + g * 512 + ((s * 16) ^ swz)) = v;
        }
    }
    __syncthreads();

    const int c0 = w * 16 + lr;

    // ---- GEMM1: nin(16x256) @ nW1
    f32x4 acc1 = {};
#pragma unroll
    for (int kk = 0; kk < 8; ++kk) {
        const short8 bf = nw1p[(kk * 8 + w) * 64 + lane];
        const short8 af = *(const short8*)(smem + lr * 512 +
                            ((kk * 64 + lq * 16) ^ ((lr & 7) << 4)));
        acc1 = __builtin_amdgcn_mfma_f32_16x16x32_bf16(af, bf, acc1, 0, 0, 0);
    }
    __syncthreads();
    {
        const float bb = nb1[c0];
#pragma unroll
        for (int reg = 0; reg < 4; ++reg) {
            const int r = lq * 4 + reg;
            const float v = silu_f(acc1[reg] + bb);
            *(unsigned short*)(smem + 8192 + r * 256 + ((c0 * 2) ^ ((r & 7) << 4))) = f2bf(v);
        }
    }
    __syncthreads();
    // ---- GEMM2: hid(16x128) @ nW2
    f32x4 acc2 = {};
#pragma unroll
    for (int kk = 0; kk < 4; ++kk) {
        const short8 bf = nw2p[(kk * 8 + w) * 64 + lane];
        const short8 af = *(const short8*)(smem + 8192 + lr * 256 +
                            ((kk * 64 + lq * 16) ^ ((lr & 7) << 4)));
        acc2 = __builtin_amdgcn_mfma_f32_16x16x32_bf16(af, bf, acc2, 0, 0, 0);
    }
    // ---- epilogue 2: residual; write h (f32/bf16/out); stage hnew
    {
        const float bb = nb2[c0];
#pragma unroll
        for (int reg = 0; reg < 4; ++reg) {
            const int r = lq * 4 + reg;
            const size_t gi = (size_t)(nb + r) * HID + c0;
            const float hnew = h_ws[gi] + acc2[reg] + bb;
            h_ws[gi] = hnew;
            h_bf[gi] = f2bf(hnew);
            if (write_out) out[gi] = hnew;
            *(unsigned short*)(smem + 12288 + r * 256 + ((c0 * 2) ^ ((r & 7) << 4))) = f2bf(hnew);
        }
    }
    __syncthreads();
    // ---- hr1b for next layer: hnew(16x128) @ W1a_next + b1_next
    if (w1a_next) {
        f32x4 acch = {};
#pragma unroll
        for (int kk = 0; kk < 4; ++kk) {
            const short8 bf = w1a_next[(kk * 8 + w) * 64 + lane];
            const short8 af = *(const short8*)(smem + 12288 + lr * 256 +
                                ((kk * 64 + lq * 16) ^ ((lr & 7) << 4)));
            acch = __builtin_amdgcn_mfma_f32_16x16x32_bf16(af, bf, acch, 0, 0, 0);
        }
        const float bb = b1_next[c0];
#pragma unroll
        for (int reg = 0; reg < 4; ++reg) {
            const int r = lq * 4 + reg;
            hr1[(size_t)(nb + r) * HID + c0] = acch[reg] + bb;
        }
    }
    // ---- coordinate update
    if (do_coord) {
        const int nl = t >> 5, sub = t & 31;
        const int n = nb + nl;
        const int rl = n & 63, base = n & ~63;
        const float xi0 = x_in[n * 3 + 0], xi1 = x_in[n * 3 + 1], xi2 = x_in[n * 3 + 2];
        float p0 = 0, p1 = 0, p2 = 0;
#pragma unroll
        for (int kk = 0; kk < 2; ++kk) {
            const int k = sub + kk * 32;
            if (k < DEG) {
                const int e = n * DEG + k;
                const int col = base + k + (k >= rl ? 1 : 0);
                const float c = c_ws[e];
                p0 += c * (xi0 - x_in[col * 3 + 0]);
                p1 += c * (xi1 - x_in[col * 3 + 1]);
                p2 += c * (xi2 - x_in[col * 3 + 2]);
            }
        }
#pragma unroll
        for (int off = 1; off < 32; off <<= 1) {
            p0 += __shfl_xor(p0, off);
            p1 += __shfl_xor(p1, off);
            p2 += __shfl_xor(p2, off);
        }
        if (sub == 0) {
            const float inv = 1.0f / DEG;
            x_out[n * 3 + 0] = xi0 + p0 * inv;
            x_out[n * 3 + 1] = xi1 + p1 * inv;
            x_out[n * 3 + 2] = xi2 + p2 * inv;
        }
    }
}

extern "C" void kernel_launch(void* const* d_in, const int* in_sizes, int n_in,
                              void* d_out, int out_size, void* d_ws, size_t ws_size,
                              hipStream_t stream)
{
    const float* h_in  = (const float*)d_in[0];
    const float* x_in  = (const float*)d_in[1];
    const float* ea0   = (const float*)d_in[4];
    const float* emb_w = (const float*)d_in[5];
    const float* emb_b = (const float*)d_in[6];
    const float* eW1   = (const float*)d_in[7];
    const float* eB1   = (const float*)d_in[8];
    const float* eW2   = (const float*)d_in[9];
    const float* eB2   = (const float*)d_in[10];
    const float* nW1   = (const float*)d_in[11];
    const float* nB1   = (const float*)d_in[12];
    const float* nW2   = (const float*)d_in[13];
    const float* nB2   = (const float*)d_in[14];
    const float* cW1   = (const float*)d_in[15];
    const float* cB1   = (const float*)d_in[16];
    const float* cW2   = (const float*)d_in[17];
    float* out = (float*)d_out;

    // bf16 edge features aliased over f32 edge_attr (256B used of each 512B row;
    // per-edge byte ranges coincide -> block-local in-place conversion, no race)
    unsigned short* ea_bf = (unsigned short*)d_in[4];

    char* p = (char*)d_ws;
    float* h_ws = (float*)p;                    p += (size_t)NNODES * HID * 4;
    unsigned short* h_bf = (unsigned short*)p;  p += (size_t)NNODES * HID * 2;
    float* agg  = (float*)p;                    p += (size_t)NNODES * HID * 4;
    float* hr1  = (float*)p;                    p += (size_t)NNODES * HID * 4;
    float* x_a  = (float*)p;                    p += NNODES * 3 * 4 + 16;
    float* x_b  = (float*)p;                    p += NNODES * 3 * 4 + 16;
    float* c_ws = (float*)p;                    p += (size_t)NEDGES * 4;
    unsigned short* w1p  = (unsigned short*)p;  p += (size_t)NLAYER * 8 * 8 * 64 * 8 * 2;
    unsigned short* w1a  = (unsigned short*)p;  p += (size_t)NLAYER * 4 * 8 * 64 * 8 * 2;
    unsigned short* w2p  = (unsigned short*)p;  p += (size_t)NLAYER * 4 * 8 * 64 * 8 * 2;
    unsigned short* cw1p = (unsigned short*)p;  p += (size_t)NLAYER * 4 * 8 * 64 * 8 * 2;
    unsigned short* nw1p = (unsigned short*)p;  p += (size_t)NLAYER * 8 * 8 * 64 * 8 * 2;
    unsigned short* nw2p = (unsigned short*)p;  p += (size_t)NLAYER * 4 * 8 * 64 * 8 * 2;

    const int SL8 = 8 * 8 * 64 * 8;
    const int SL4 = 4 * 8 * 64 * 8;

    pack_all_kernel<<<1024, 64, 0, stream>>>(eW1, eW2, cW1, nW1, nW2,
                                             w1p, w1a, w2p, cw1p, nw1p, nw2p);

    embed_kernel<<<NNODES, HID, 0, stream>>>(h_in, emb_w, emb_b, eW1, eB1,
                                             h_ws, h_bf, hr1, agg, x_in, x_a);

    float* xc = x_a;
    float* xn = x_b;
    for (int i = 0; i < NLAYER; ++i) {
        edge_mfma_kernel<<<EBLOCKS, 512, 0, stream>>>(
            h_bf, xc, ea0, ea_bf, (i == 0) ? 1 : 0, hr1,
            (const short8*)(w1p + (size_t)i * SL8),
            eW1 + ((size_t)i * K1 + 256) * HID,
            (const short8*)(w2p + (size_t)i * SL4), eB2 + i * HID,
            (const short8*)(cw1p + (size_t)i * SL4), cB1 + i * HID,
            cW2 + (size_t)i * HID, c_ws, agg);
        node_mfma_kernel<<<NBLOCKS, 512, 0, stream>>>(
            h_ws, h_bf, agg,
            (const short8*)(nw1p + (size_t)i * SL8), nB1 + i * HID,
            (const short8*)(nw2p + (size_t)i * SL4), nB2 + i * HID,
            (i < NLAYER - 1) ? (const short8*)(w1a + (size_t)(i + 1) * SL4) : (const short8*)nullptr,
            (i < NLAYER - 1) ? (eB1 + (size_t)(i + 1) * HID) : nullptr,
            hr1, xc, xn, c_ws,
            out, (i == NLAYER - 1) ? 1 : 0, (i < NLAYER - 1) ? 1 : 0);
        float* tmp = xc; xc = xn; xn = tmp;
    }
}